// Round 3
// baseline (258.515 us; speedup 1.0000x reference)
//
#include <hip/hip_runtime.h>
#include <stdint.h>

#define D_MODEL 1024
#define NHEAD 16
#define HD 64
#define BB 2
#define TT 2048
#define MR (BB*TT)   // 4096 rows

typedef unsigned short u16;
typedef __bf16 bf16x8 __attribute__((ext_vector_type(8)));
typedef u16 u16x8 __attribute__((ext_vector_type(8)));
typedef float f32x4 __attribute__((ext_vector_type(4)));

__device__ __forceinline__ u16 f2bf(float f) {
  union { float f; unsigned u; } v; v.f = f;
  unsigned r = v.u + 0x7FFFu + ((v.u >> 16) & 1u);
  return (u16)(r >> 16);
}

__device__ __forceinline__ void gload_lds16(const void* g, void* l) {
  __builtin_amdgcn_global_load_lds(
      (const __attribute__((address_space(1))) void*)g,
      (__attribute__((address_space(3))) void*)l, 16, 0, 0);
}

// ---------------- f32 -> bf16 convert (vectorized) ----------------
__global__ void k_f32_to_bf16(const float* __restrict__ src, u16* __restrict__ dst, int n4) {
  int idx = blockIdx.x * blockDim.x + threadIdx.x;
  int stride = gridDim.x * blockDim.x;
  for (int i = idx; i < n4; i += stride) {
    float4 v = reinterpret_cast<const float4*>(src)[i];
    ushort4 o;
    o.x = f2bf(v.x); o.y = f2bf(v.y); o.z = f2bf(v.z); o.w = f2bf(v.w);
    reinterpret_cast<ushort4*>(dst)[i] = o;
  }
}

// ---------------- transpose f32 [K][N] -> bf16 [N][K] ----------------
__global__ void k_transpose_f32_bf16(const float* __restrict__ src, u16* __restrict__ dst,
                                     int K, int N) {
  __shared__ float tile[32][33];
  int n0 = blockIdx.x * 32, k0 = blockIdx.y * 32;
  int tx = threadIdx.x, ty = threadIdx.y;  // block (32,8)
  #pragma unroll
  for (int i = 0; i < 32; i += 8)
    tile[ty + i][tx] = src[(size_t)(k0 + ty + i) * N + n0 + tx];
  __syncthreads();
  #pragma unroll
  for (int i = 0; i < 32; i += 8)
    dst[(size_t)(n0 + ty + i) * K + k0 + tx] = f2bf(tile[tx][ty + i]);
}

// ---------------- bf16 GEMM, B^T input, 128x128 tile ----------------
// MODE 0: qkv projection -> scatter Q/K into [B][H][T][64], V into [B][H][64][T] (transposed), +bias
// MODE 1: out = A @ B + bias, f32 row-major
template<int MODE>
__global__ __launch_bounds__(256)
void k_gemm_bt(const u16* __restrict__ A, const u16* __restrict__ Bt,
               const float* __restrict__ bias,
               u16* __restrict__ q_out, u16* __restrict__ k_out, u16* __restrict__ v_out,
               float* __restrict__ c_out, int M, int N, int K)
{
  __shared__ __align__(16) u16 a_sh[128 * 64];
  __shared__ __align__(16) u16 b_sh[128 * 64];
  const int u = threadIdx.x;
  const int lane = u & 63;
  const int w = u >> 6;
  const int wr = w >> 1, wc = w & 1;
  const int m0 = blockIdx.y * 128;
  const int n0 = blockIdx.x * 128;
  const int r = lane & 15, q4 = lane >> 4;

  f32x4 acc[4][4];
  #pragma unroll
  for (int i = 0; i < 4; i++)
    #pragma unroll
    for (int j = 0; j < 4; j++) acc[i][j] = {0.f, 0.f, 0.f, 0.f};

  const int arow = u >> 3;        // 0..31
  const int acol = (u & 7) * 8;   // 0..56
  const u16* Ag = A + (size_t)(m0 + arow) * K + acol;
  const u16* Bg = Bt + (size_t)(n0 + arow) * K + acol;

  for (int k0 = 0; k0 < K; k0 += 64) {
    #pragma unroll
    for (int i = 0; i < 4; i++) {
      gload_lds16(Ag + (size_t)i * 32 * K + k0, &a_sh[(i * 32 + w * 8) * 64]);
      gload_lds16(Bg + (size_t)i * 32 * K + k0, &b_sh[(i * 32 + w * 8) * 64]);
    }
    __syncthreads();
    #pragma unroll
    for (int kc = 0; kc < 2; kc++) {
      bf16x8 af[4], bfr[4];
      #pragma unroll
      for (int m = 0; m < 4; m++)
        af[m] = *reinterpret_cast<const bf16x8*>(&a_sh[(wr * 64 + m * 16 + r) * 64 + kc * 32 + q4 * 8]);
      #pragma unroll
      for (int n = 0; n < 4; n++)
        bfr[n] = *reinterpret_cast<const bf16x8*>(&b_sh[(wc * 64 + n * 16 + r) * 64 + kc * 32 + q4 * 8]);
      #pragma unroll
      for (int m = 0; m < 4; m++)
        #pragma unroll
        for (int n = 0; n < 4; n++)
          acc[m][n] = __builtin_amdgcn_mfma_f32_16x16x32_bf16(af[m], bfr[n], acc[m][n], 0, 0, 0);
    }
    __syncthreads();
  }

  if (MODE == 0) {
    #pragma unroll
    for (int n = 0; n < 4; n++) {
      int gcol = n0 + wc * 64 + n * 16 + r;
      int which = gcol >> 10;   // uniform within fragment (16-aligned ranges)
      int rem = gcol & 1023;
      int h = rem >> 6, d = rem & 63;
      float bv = bias[gcol];
      #pragma unroll
      for (int m = 0; m < 4; m++) {
        #pragma unroll
        for (int reg = 0; reg < 4; reg++) {
          int grow = m0 + wr * 64 + m * 16 + q4 * 4 + reg;
          int b = grow >> 11, t = grow & 2047;
          u16 val = f2bf(acc[m][n][reg] + bv);
          if (which == 0)
            q_out[(((size_t)(b * NHEAD + h) * TT + t) << 6) + d] = val;
          else if (which == 1)
            k_out[(((size_t)(b * NHEAD + h) * TT + t) << 6) + d] = val;
          else  // V transposed: [b][h][d][t]
            v_out[(((size_t)(b * NHEAD + h) * HD + d) * TT) + t] = val;
        }
      }
    }
  } else {
    #pragma unroll
    for (int m = 0; m < 4; m++) {
      #pragma unroll
      for (int reg = 0; reg < 4; reg++) {
        int grow = m0 + wr * 64 + m * 16 + q4 * 4 + reg;
        #pragma unroll
        for (int n = 0; n < 4; n++) {
          int gcol = n0 + wc * 64 + n * 16 + r;
          c_out[(size_t)grow * N + gcol] = acc[m][n][reg] + bias[gcol];
        }
      }
    }
  }
}

// ---------------- causal flash attention, barrier-free, 128-col steps ----------------
// 1024 blocks of 256. XCD swizzle groups all 32 blocks of a head on one XCD.
// Each wave independently owns 16 q-rows; block-balanced causal map:
//   wt = (w<2) ? 2i+w : 127-2i-(w&1). Two 64-col k-tiles per iteration; one
//   softmax pass per 128 cols. P transpose via private per-wave LDS slice.
#define SCL2 0.18033688011112042f   // 0.125 * log2(e)
__global__ __launch_bounds__(256)
void k_attn(const u16* __restrict__ Q, const u16* __restrict__ Kk,
            const u16* __restrict__ Vt, u16* __restrict__ Y)
{
  __shared__ __align__(16) u16 p_sh[4][16 * 136];

  const int u = threadIdx.x;
  const int lane = u & 63;
  const int w = u >> 6;
  const int r = lane & 15, q4 = lane >> 4;
  const int task = (blockIdx.x & 7) * 128 + (blockIdx.x >> 3);
  const int bh = task >> 5;
  const int i = task & 31;
  const int wt = (w < 2) ? (2 * i + w) : (127 - 2 * i - (w & 1));
  const int b = bh >> 4, h = bh & 15;
  const size_t head_off = (size_t)bh * TT * HD;   // Q,K: [t][d];  Vt: [d][t]
  const int q0 = wt * 16;
  const int lastkt = wt >> 2;     // last 64-col tile index (inclusive)

  bf16x8 qf[2];
  qf[0] = *reinterpret_cast<const bf16x8*>(&Q[head_off + (size_t)(q0 + r) * HD + q4 * 8]);
  qf[1] = *reinterpret_cast<const bf16x8*>(&Q[head_off + (size_t)(q0 + r) * HD + 32 + q4 * 8]);

  f32x4 of[4];
  #pragma unroll
  for (int k = 0; k < 4; k++) of[k] = {0.f, 0.f, 0.f, 0.f};
  float m_run[4], l_run[4];
  #pragma unroll
  for (int k = 0; k < 4; k++) { m_run[k] = -1e30f; l_run[k] = 0.f; }

  u16* pw = &p_sh[w][0];
  const int qg = q0 + q4 * 4;     // + reg = this thread's q rows

  // ---- full 128-col (2-tile) iterations ----
  int kt2 = 0;
  for (; kt2 + 1 <= lastkt; kt2 += 2) {
    // S over 8 column-fragments (128 cols)
    f32x4 sf[8];
    #pragma unroll
    for (int n = 0; n < 8; n++) {
      const int krow = kt2 * 64 + n * 16 + r;
      f32x4 a = {0.f, 0.f, 0.f, 0.f};
      #pragma unroll
      for (int kc = 0; kc < 2; kc++) {
        bf16x8 kf = *reinterpret_cast<const bf16x8*>(
            &Kk[head_off + (size_t)krow * HD + kc * 32 + q4 * 8]);
        a = __builtin_amdgcn_mfma_f32_16x16x32_bf16(qf[kc], kf, a, 0, 0, 0);
      }
      sf[n] = a;
    }
    // issue V loads now; latency hides under softmax
    bf16x8 vf[4][4];
    #pragma unroll
    for (int kc = 0; kc < 4; kc++)
      #pragma unroll
      for (int d0 = 0; d0 < 4; d0++)
        vf[kc][d0] = *reinterpret_cast<const bf16x8*>(
            &Vt[head_off + (size_t)(d0 * 16 + r) * TT + kt2 * 64 + kc * 32 + q4 * 8]);

    // scale into exp2 domain + mask (only the t1==lastkt case can need it)
    const bool diag = (kt2 + 1 == lastkt);
    #pragma unroll
    for (int n = 0; n < 8; n++) {
      #pragma unroll
      for (int reg = 0; reg < 4; reg++) {
        float s = sf[n][reg] * SCL2;
        if (diag && n >= 4) {
          int kg = kt2 * 64 + n * 16 + r;
          if (kg > qg + reg) s = -1e30f;
        }
        sf[n][reg] = s;
      }
    }
    // online softmax over 128 cols
    float alpha[4];
    #pragma unroll
    for (int reg = 0; reg < 4; reg++) {
      float v = sf[0][reg];
      #pragma unroll
      for (int n = 1; n < 8; n++) v = fmaxf(v, sf[n][reg]);
      #pragma unroll
      for (int off = 1; off < 16; off <<= 1) v = fmaxf(v, __shfl_xor(v, off));
      float mnew = fmaxf(m_run[reg], v);
      alpha[reg] = __builtin_amdgcn_exp2f(m_run[reg] - mnew);
      m_run[reg] = mnew;
    }
    float rs[4] = {0.f, 0.f, 0.f, 0.f};
    #pragma unroll
    for (int n = 0; n < 8; n++) {
      #pragma unroll
      for (int reg = 0; reg < 4; reg++) {
        float p = __builtin_amdgcn_exp2f(sf[n][reg] - m_run[reg]);
        sf[n][reg] = p;
        rs[reg] += p;
      }
    }
    #pragma unroll
    for (int reg = 0; reg < 4; reg++) {
      float v = rs[reg];
      #pragma unroll
      for (int off = 1; off < 16; off <<= 1) v += __shfl_xor(v, off);
      l_run[reg] = l_run[reg] * alpha[reg] + v;
    }
    #pragma unroll
    for (int d0 = 0; d0 < 4; d0++)
      #pragma unroll
      for (int reg = 0; reg < 4; reg++)
        of[d0][reg] *= alpha[reg];

    // P transpose through private LDS slice (no barrier)
    #pragma unroll
    for (int n = 0; n < 8; n++)
      #pragma unroll
      for (int reg = 0; reg < 4; reg++)
        pw[(q4 * 4 + reg) * 136 + n * 16 + r] = f2bf(sf[n][reg]);

    // O += P @ V over 128 k-cols
    #pragma unroll
    for (int kc = 0; kc < 4; kc++) {
      bf16x8 pa = *reinterpret_cast<const bf16x8*>(&pw[r * 136 + kc * 32 + q4 * 8]);
      #pragma unroll
      for (int d0 = 0; d0 < 4; d0++)
        of[d0] = __builtin_amdgcn_mfma_f32_16x16x32_bf16(pa, vf[kc][d0], of[d0], 0, 0, 0);
    }
  }

  // ---- tail single 64-col tile (always the masked diagonal) ----
  if (kt2 == lastkt) {
    const int kt = lastkt;
    f32x4 sf[4];
    #pragma unroll
    for (int n = 0; n < 4; n++) {
      const int krow = kt * 64 + n * 16 + r;
      f32x4 a = {0.f, 0.f, 0.f, 0.f};
      #pragma unroll
      for (int kc = 0; kc < 2; kc++) {
        bf16x8 kf = *reinterpret_cast<const bf16x8*>(
            &Kk[head_off + (size_t)krow * HD + kc * 32 + q4 * 8]);
        a = __builtin_amdgcn_mfma_f32_16x16x32_bf16(qf[kc], kf, a, 0, 0, 0);
      }
      sf[n] = a;
    }
    bf16x8 vf[2][4];
    #pragma unroll
    for (int kc = 0; kc < 2; kc++)
      #pragma unroll
      for (int d0 = 0; d0 < 4; d0++)
        vf[kc][d0] = *reinterpret_cast<const bf16x8*>(
            &Vt[head_off + (size_t)(d0 * 16 + r) * TT + kt * 64 + kc * 32 + q4 * 8]);

    #pragma unroll
    for (int n = 0; n < 4; n++) {
      int kg = kt * 64 + n * 16 + r;
      #pragma unroll
      for (int reg = 0; reg < 4; reg++) {
        float s = sf[n][reg] * SCL2;
        if (kg > qg + reg) s = -1e30f;
        sf[n][reg] = s;
      }
    }
    float alpha[4];
    #pragma unroll
    for (int reg = 0; reg < 4; reg++) {
      float v = fmaxf(fmaxf(sf[0][reg], sf[1][reg]), fmaxf(sf[2][reg], sf[3][reg]));
      #pragma unroll
      for (int off = 1; off < 16; off <<= 1) v = fmaxf(v, __shfl_xor(v, off));
      float mnew = fmaxf(m_run[reg], v);
      alpha[reg] = __builtin_amdgcn_exp2f(m_run[reg] - mnew);
      m_run[reg] = mnew;
    }
    float rs[4] = {0.f, 0.f, 0.f, 0.f};
    #pragma unroll
    for (int n = 0; n < 4; n++) {
      #pragma unroll
      for (int reg = 0; reg < 4; reg++) {
        float p = __builtin_amdgcn_exp2f(sf[n][reg] - m_run[reg]);
        sf[n][reg] = p;
        rs[reg] += p;
      }
    }
    #pragma unroll
    for (int reg = 0; reg < 4; reg++) {
      float v = rs[reg];
      #pragma unroll
      for (int off = 1; off < 16; off <<= 1) v += __shfl_xor(v, off);
      l_run[reg] = l_run[reg] * alpha[reg] + v;
    }
    #pragma unroll
    for (int d0 = 0; d0 < 4; d0++)
      #pragma unroll
      for (int reg = 0; reg < 4; reg++)
        of[d0][reg] *= alpha[reg];
    #pragma unroll
    for (int n = 0; n < 4; n++)
      #pragma unroll
      for (int reg = 0; reg < 4; reg++)
        pw[(q4 * 4 + reg) * 136 + n * 16 + r] = f2bf(sf[n][reg]);
    #pragma unroll
    for (int kc = 0; kc < 2; kc++) {
      bf16x8 pa = *reinterpret_cast<const bf16x8*>(&pw[r * 136 + kc * 32 + q4 * 8]);
      #pragma unroll
      for (int d0 = 0; d0 < 4; d0++)
        of[d0] = __builtin_amdgcn_mfma_f32_16x16x32_bf16(pa, vf[kc][d0], of[d0], 0, 0, 0);
    }
  }

  // epilogue: Y[(b*T + t)*1024 + h*64 + d], bf16
  #pragma unroll
  for (int d0 = 0; d0 < 4; d0++) {
    #pragma unroll
    for (int reg = 0; reg < 4; reg++) {
      int t = q0 + q4 * 4 + reg;
      float val = of[d0][reg] / l_run[reg];
      Y[((size_t)(b * TT + t) << 10) + h * 64 + d0 * 16 + r] = f2bf(val);
    }
  }
}

// ---------------- host launcher ----------------
extern "C" void kernel_launch(void* const* d_in, const int* in_sizes, int n_in,
                              void* d_out, int out_size, void* d_ws, size_t ws_size,
                              hipStream_t stream) {
  const float* x     = (const float*)d_in[0];
  const float* w_qkv = (const float*)d_in[1];
  const float* b_qkv = (const float*)d_in[2];
  const float* w_out = (const float*)d_in[3];
  const float* b_out = (const float*)d_in[4];
  float* out = (float*)d_out;

  uint8_t* ws = (uint8_t*)d_ws;
  u16* xb    = (u16*)(ws);                    // 8 MB  (reused as y_heads later)
  u16* wqkvT = (u16*)(ws + (8u  << 20));      // 6 MB
  u16* woutT = (u16*)(ws + (14u << 20));      // 2 MB
  u16* Qh    = (u16*)(ws + (16u << 20));      // 8 MB
  u16* Kh    = (u16*)(ws + (24u << 20));      // 8 MB
  u16* Vth   = (u16*)(ws + (32u << 20));      // 8 MB  (transposed V)

  k_f32_to_bf16<<<1024, 256, 0, stream>>>(x, xb, (MR * D_MODEL) / 4);
  k_transpose_f32_bf16<<<dim3(3 * D_MODEL / 32, D_MODEL / 32), dim3(32, 8), 0, stream>>>(
      w_qkv, wqkvT, D_MODEL, 3 * D_MODEL);
  k_transpose_f32_bf16<<<dim3(D_MODEL / 32, D_MODEL / 32), dim3(32, 8), 0, stream>>>(
      w_out, woutT, D_MODEL, D_MODEL);

  k_gemm_bt<0><<<dim3(3 * D_MODEL / 128, MR / 128), 256, 0, stream>>>(
      xb, wqkvT, b_qkv, Qh, Kh, Vth, nullptr, MR, 3 * D_MODEL, D_MODEL);

  u16* Yh = xb;  // reuse x-bf16 region
  k_attn<<<dim3(BB * NHEAD * 32), 256, 0, stream>>>(Qh, Kh, Vth, Yh);

  k_gemm_bt<1><<<dim3(D_MODEL / 128, MR / 128), 256, 0, stream>>>(
      Yh, woutT, b_out, nullptr, nullptr, nullptr, out, MR, D_MODEL, D_MODEL);
}

// Round 4
// 229.189 us; speedup vs baseline: 1.1280x; 1.1280x over previous
//
#include <hip/hip_runtime.h>
#include <stdint.h>

#define D_MODEL 1024
#define NHEAD 16
#define HD 64
#define BB 2
#define TT 2048
#define MR (BB*TT)   // 4096 rows

typedef unsigned short u16;
typedef __bf16 bf16x8 __attribute__((ext_vector_type(8)));
typedef u16 u16x8 __attribute__((ext_vector_type(8)));
typedef float f32x4 __attribute__((ext_vector_type(4)));

__device__ __forceinline__ u16 f2bf(float f) {
  union { float f; unsigned u; } v; v.f = f;
  unsigned r = v.u + 0x7FFFu + ((v.u >> 16) & 1u);
  return (u16)(r >> 16);
}
__device__ __forceinline__ unsigned pack2bf(float a, float b) {
  return (unsigned)f2bf(a) | ((unsigned)f2bf(b) << 16);
}

__device__ __forceinline__ void gload_lds16(const void* g, void* l) {
  __builtin_amdgcn_global_load_lds(
      (const __attribute__((address_space(1))) void*)g,
      (__attribute__((address_space(3))) void*)l, 16, 0, 0);
}

// ---------------- f32 -> bf16 convert (vectorized) ----------------
__global__ void k_f32_to_bf16(const float* __restrict__ src, u16* __restrict__ dst, int n4) {
  int idx = blockIdx.x * blockDim.x + threadIdx.x;
  int stride = gridDim.x * blockDim.x;
  for (int i = idx; i < n4; i += stride) {
    float4 v = reinterpret_cast<const float4*>(src)[i];
    ushort4 o;
    o.x = f2bf(v.x); o.y = f2bf(v.y); o.z = f2bf(v.z); o.w = f2bf(v.w);
    reinterpret_cast<ushort4*>(dst)[i] = o;
  }
}

// ---------------- transpose f32 [K][N] -> bf16 [N][K] ----------------
__global__ void k_transpose_f32_bf16(const float* __restrict__ src, u16* __restrict__ dst,
                                     int K, int N) {
  __shared__ float tile[32][33];
  int n0 = blockIdx.x * 32, k0 = blockIdx.y * 32;
  int tx = threadIdx.x, ty = threadIdx.y;  // block (32,8)
  #pragma unroll
  for (int i = 0; i < 32; i += 8)
    tile[ty + i][tx] = src[(size_t)(k0 + ty + i) * N + n0 + tx];
  __syncthreads();
  #pragma unroll
  for (int i = 0; i < 32; i += 8)
    dst[(size_t)(n0 + ty + i) * K + k0 + tx] = f2bf(tile[tx][ty + i]);
}

// ---------------- bf16 GEMM, B^T input, 128x128 tile ----------------
// MODE 0: qkv projection -> scatter Q/K into [B][H][T][64], V into [B][H][64][T] (transposed), +bias
// MODE 1: out = A @ B + bias, f32 row-major
template<int MODE>
__global__ __launch_bounds__(256)
void k_gemm_bt(const u16* __restrict__ A, const u16* __restrict__ Bt,
               const float* __restrict__ bias,
               u16* __restrict__ q_out, u16* __restrict__ k_out, u16* __restrict__ v_out,
               float* __restrict__ c_out, int M, int N, int K)
{
  __shared__ __align__(16) u16 a_sh[128 * 64];
  __shared__ __align__(16) u16 b_sh[128 * 64];
  const int u = threadIdx.x;
  const int lane = u & 63;
  const int w = u >> 6;
  const int wr = w >> 1, wc = w & 1;
  const int m0 = blockIdx.y * 128;
  const int n0 = blockIdx.x * 128;
  const int r = lane & 15, q4 = lane >> 4;

  f32x4 acc[4][4];
  #pragma unroll
  for (int i = 0; i < 4; i++)
    #pragma unroll
    for (int j = 0; j < 4; j++) acc[i][j] = {0.f, 0.f, 0.f, 0.f};

  const int arow = u >> 3;        // 0..31
  const int acol = (u & 7) * 8;   // 0..56
  const u16* Ag = A + (size_t)(m0 + arow) * K + acol;
  const u16* Bg = Bt + (size_t)(n0 + arow) * K + acol;

  for (int k0 = 0; k0 < K; k0 += 64) {
    #pragma unroll
    for (int i = 0; i < 4; i++) {
      gload_lds16(Ag + (size_t)i * 32 * K + k0, &a_sh[(i * 32 + w * 8) * 64]);
      gload_lds16(Bg + (size_t)i * 32 * K + k0, &b_sh[(i * 32 + w * 8) * 64]);
    }
    __syncthreads();
    #pragma unroll
    for (int kc = 0; kc < 2; kc++) {
      bf16x8 af[4], bfr[4];
      #pragma unroll
      for (int m = 0; m < 4; m++)
        af[m] = *reinterpret_cast<const bf16x8*>(&a_sh[(wr * 64 + m * 16 + r) * 64 + kc * 32 + q4 * 8]);
      #pragma unroll
      for (int n = 0; n < 4; n++)
        bfr[n] = *reinterpret_cast<const bf16x8*>(&b_sh[(wc * 64 + n * 16 + r) * 64 + kc * 32 + q4 * 8]);
      #pragma unroll
      for (int m = 0; m < 4; m++)
        #pragma unroll
        for (int n = 0; n < 4; n++)
          acc[m][n] = __builtin_amdgcn_mfma_f32_16x16x32_bf16(af[m], bfr[n], acc[m][n], 0, 0, 0);
    }
    __syncthreads();
  }

  if (MODE == 0) {
    #pragma unroll
    for (int n = 0; n < 4; n++) {
      int gcol = n0 + wc * 64 + n * 16 + r;
      int which = gcol >> 10;   // uniform within fragment (16-aligned ranges)
      int rem = gcol & 1023;
      int h = rem >> 6, d = rem & 63;
      float bv = bias[gcol];
      #pragma unroll
      for (int m = 0; m < 4; m++) {
        #pragma unroll
        for (int reg = 0; reg < 4; reg++) {
          int grow = m0 + wr * 64 + m * 16 + q4 * 4 + reg;
          int b = grow >> 11, t = grow & 2047;
          u16 val = f2bf(acc[m][n][reg] + bv);
          if (which == 0)
            q_out[(((size_t)(b * NHEAD + h) * TT + t) << 6) + d] = val;
          else if (which == 1)
            k_out[(((size_t)(b * NHEAD + h) * TT + t) << 6) + d] = val;
          else  // V transposed: [b][h][d][t]
            v_out[(((size_t)(b * NHEAD + h) * HD + d) * TT) + t] = val;
        }
      }
    }
  } else {
    #pragma unroll
    for (int m = 0; m < 4; m++) {
      #pragma unroll
      for (int reg = 0; reg < 4; reg++) {
        int grow = m0 + wr * 64 + m * 16 + q4 * 4 + reg;
        #pragma unroll
        for (int n = 0; n < 4; n++) {
          int gcol = n0 + wc * 64 + n * 16 + r;
          c_out[(size_t)grow * N + gcol] = acc[m][n][reg] + bias[gcol];
        }
      }
    }
  }
}

// ---------------- causal flash attention, barrier-free, swapped-operand softmax ----------------
// 1024 blocks of 256 (4 independent waves, 16 q-rows each). XCD swizzle groups
// each head's 32 blocks on one XCD (K/V L2-resident). Swapped MFMA operands:
//   S^T = mfma(K, Q)  -> lane owns 16 P-values of ONE q-row  (in-lane softmax)
//   O^T = mfma(V, P)  -> cols = q, so alpha/l stay per-lane scalars
#define SCL2 0.18033688011112042f   // 0.125 * log2(e)
__global__ __launch_bounds__(256)
void k_attn(const u16* __restrict__ Q, const u16* __restrict__ Kk,
            const u16* __restrict__ Vt, u16* __restrict__ Y)
{
  __shared__ __align__(16) u16 p_sh[4][16 * 72];   // per-wave [q][k] P tile

  const int u = threadIdx.x;
  const int lane = u & 63;
  const int w = u >> 6;
  const int r = lane & 15, q4 = lane >> 4;
  const int task = (blockIdx.x & 7) * 128 + (blockIdx.x >> 3);
  const int bh = task >> 5;
  const int i = task & 31;
  const int wt = (w < 2) ? (2 * i + w) : (127 - 2 * i - (w & 1));
  const int b = bh >> 4, h = bh & 15;
  const size_t head_off = (size_t)bh * TT * HD;   // Q,K: [t][d];  Vt: [d][t]
  const int q0 = wt * 16;
  const int lastkt = wt >> 2;
  const int myq = q0 + r;          // this lane's q-row

  bf16x8 qf[2];
  qf[0] = *reinterpret_cast<const bf16x8*>(&Q[head_off + (size_t)myq * HD + q4 * 8]);
  qf[1] = *reinterpret_cast<const bf16x8*>(&Q[head_off + (size_t)myq * HD + 32 + q4 * 8]);

  f32x4 of[4];
  #pragma unroll
  for (int k = 0; k < 4; k++) of[k] = {0.f, 0.f, 0.f, 0.f};
  float m_run = -1e30f;
  float lp = 0.f;                  // per-lane partial denominator

  u16* pw = &p_sh[w][0];

  for (int kt = 0; kt <= lastkt; kt++) {
    const u16* Kt = &Kk[head_off + ((size_t)kt * 64) * HD];

    // S^T = mfma(K, Q): sf[n][reg] = S[k = kt*64 + n*16 + q4*4 + reg][q = myq]
    f32x4 sf[4];
    __builtin_amdgcn_s_setprio(1);
    #pragma unroll
    for (int n = 0; n < 4; n++) {
      f32x4 a = {0.f, 0.f, 0.f, 0.f};
      #pragma unroll
      for (int kc = 0; kc < 2; kc++) {
        bf16x8 kf = *reinterpret_cast<const bf16x8*>(&Kt[(size_t)(n * 16 + r) * HD + kc * 32 + q4 * 8]);
        a = __builtin_amdgcn_mfma_f32_16x16x32_bf16(kf, qf[kc], a, 0, 0, 0);
      }
      sf[n] = a;
    }
    __builtin_amdgcn_s_setprio(0);

    // prefetch V fragments (A-operand rows = d); latency hides under softmax
    bf16x8 vf[2][4];
    #pragma unroll
    for (int kc = 0; kc < 2; kc++)
      #pragma unroll
      for (int d0 = 0; d0 < 4; d0++)
        vf[kc][d0] = *reinterpret_cast<const bf16x8*>(
            &Vt[head_off + (size_t)(d0 * 16 + r) * TT + kt * 64 + kc * 32 + q4 * 8]);

    // scale + causal mask (only diagonal tile can mask; earlier tiles all k < q0)
    #pragma unroll
    for (int n = 0; n < 4; n++) {
      #pragma unroll
      for (int reg = 0; reg < 4; reg++) {
        float s = sf[n][reg] * SCL2;
        if (kt == lastkt) {
          int kg = kt * 64 + n * 16 + q4 * 4 + reg;
          if (kg > myq) s = -1e30f;
        }
        sf[n][reg] = s;
      }
    }

    // in-lane row softmax: 16 values of one q-row per lane, + 2 shfl for the
    // cross-q4 max. Denominator kept as per-lane partial (no sum-shfl here).
    float mt = sf[0][0];
    #pragma unroll
    for (int n = 0; n < 4; n++)
      #pragma unroll
      for (int reg = 0; reg < 4; reg++) mt = fmaxf(mt, sf[n][reg]);
    mt = fmaxf(mt, __shfl_xor(mt, 16));
    mt = fmaxf(mt, __shfl_xor(mt, 32));
    float mnew = fmaxf(m_run, mt);
    float alpha = __builtin_amdgcn_exp2f(m_run - mnew);
    m_run = mnew;

    float ssum = 0.f;
    #pragma unroll
    for (int n = 0; n < 4; n++) {
      #pragma unroll
      for (int reg = 0; reg < 4; reg++) {
        float p = __builtin_amdgcn_exp2f(sf[n][reg] - mnew);
        sf[n][reg] = p;
        ssum += p;
      }
    }
    lp = lp * alpha + ssum;
    #pragma unroll
    for (int d0 = 0; d0 < 4; d0++)
      #pragma unroll
      for (int reg = 0; reg < 4; reg++)
        of[d0][reg] *= alpha;

    // P -> LDS [q][k]: lane's 4 regs are k-contiguous -> packed 8B writes
    #pragma unroll
    for (int n = 0; n < 4; n++) {
      uint2 pk;
      pk.x = pack2bf(sf[n][0], sf[n][1]);
      pk.y = pack2bf(sf[n][2], sf[n][3]);
      *reinterpret_cast<uint2*>(&pw[r * 72 + n * 16 + q4 * 4]) = pk;
    }

    // O^T += mfma(V, P): rows = d, cols = q (= this lane's row r)
    #pragma unroll
    for (int kc = 0; kc < 2; kc++) {
      bf16x8 pa = *reinterpret_cast<const bf16x8*>(&pw[r * 72 + kc * 32 + q4 * 8]);
      #pragma unroll
      for (int d0 = 0; d0 < 4; d0++)
        of[d0] = __builtin_amdgcn_mfma_f32_16x16x32_bf16(vf[kc][d0], pa, of[d0], 0, 0, 0);
    }
  }

  // epilogue: reduce per-lane partial l across the 4 q4-lanes, then packed stores.
  lp += __shfl_xor(lp, 16);
  lp += __shfl_xor(lp, 32);
  float inv = 1.0f / lp;
  const int t = q0 + r;
  #pragma unroll
  for (int d0 = 0; d0 < 4; d0++) {
    uint2 pk;
    pk.x = pack2bf(of[d0][0] * inv, of[d0][1] * inv);
    pk.y = pack2bf(of[d0][2] * inv, of[d0][3] * inv);
    *reinterpret_cast<uint2*>(&Y[((size_t)(b * TT + t) << 10) + h * 64 + d0 * 16 + q4 * 4]) = pk;
  }
}

// ---------------- host launcher ----------------
extern "C" void kernel_launch(void* const* d_in, const int* in_sizes, int n_in,
                              void* d_out, int out_size, void* d_ws, size_t ws_size,
                              hipStream_t stream) {
  const float* x     = (const float*)d_in[0];
  const float* w_qkv = (const float*)d_in[1];
  const float* b_qkv = (const float*)d_in[2];
  const float* w_out = (const float*)d_in[3];
  const float* b_out = (const float*)d_in[4];
  float* out = (float*)d_out;

  uint8_t* ws = (uint8_t*)d_ws;
  u16* xb    = (u16*)(ws);                    // 8 MB  (reused as y_heads later)
  u16* wqkvT = (u16*)(ws + (8u  << 20));      // 6 MB
  u16* woutT = (u16*)(ws + (14u << 20));      // 2 MB
  u16* Qh    = (u16*)(ws + (16u << 20));      // 8 MB
  u16* Kh    = (u16*)(ws + (24u << 20));      // 8 MB
  u16* Vth   = (u16*)(ws + (32u << 20));      // 8 MB  (transposed V)

  k_f32_to_bf16<<<1024, 256, 0, stream>>>(x, xb, (MR * D_MODEL) / 4);
  k_transpose_f32_bf16<<<dim3(3 * D_MODEL / 32, D_MODEL / 32), dim3(32, 8), 0, stream>>>(
      w_qkv, wqkvT, D_MODEL, 3 * D_MODEL);
  k_transpose_f32_bf16<<<dim3(D_MODEL / 32, D_MODEL / 32), dim3(32, 8), 0, stream>>>(
      w_out, woutT, D_MODEL, D_MODEL);

  k_gemm_bt<0><<<dim3(3 * D_MODEL / 128, MR / 128), 256, 0, stream>>>(
      xb, wqkvT, b_qkv, Qh, Kh, Vth, nullptr, MR, 3 * D_MODEL, D_MODEL);

  u16* Yh = xb;  // reuse x-bf16 region
  k_attn<<<dim3(BB * NHEAD * 32), 256, 0, stream>>>(Qh, Kh, Vth, Yh);

  k_gemm_bt<1><<<dim3(D_MODEL / 128, MR / 128), 256, 0, stream>>>(
      Yh, woutT, b_out, nullptr, nullptr, nullptr, out, MR, D_MODEL, D_MODEL);
}

// Round 5
// 185.321 us; speedup vs baseline: 1.3950x; 1.2367x over previous
//
#include <hip/hip_runtime.h>
#include <stdint.h>

#define D_MODEL 1024
#define NHEAD 16
#define HD 64
#define BB 2
#define TT 2048
#define MR (BB*TT)   // 4096 rows

typedef unsigned short u16;
typedef __bf16 bf16x8 __attribute__((ext_vector_type(8)));
typedef u16 u16x8 __attribute__((ext_vector_type(8)));
typedef float f32x4 __attribute__((ext_vector_type(4)));

__device__ __forceinline__ u16 f2bf(float f) {
  union { float f; unsigned u; } v; v.f = f;
  unsigned r = v.u + 0x7FFFu + ((v.u >> 16) & 1u);
  return (u16)(r >> 16);
}
__device__ __forceinline__ unsigned pack2bf(float a, float b) {
  return (unsigned)f2bf(a) | ((unsigned)f2bf(b) << 16);
}

__device__ __forceinline__ void gload_lds16(const void* g, void* l) {
  __builtin_amdgcn_global_load_lds(
      (const __attribute__((address_space(1))) void*)g,
      (__attribute__((address_space(3))) void*)l, 16, 0, 0);
}

// ---------------- f32 -> bf16 convert (vectorized) ----------------
__global__ void k_f32_to_bf16(const float* __restrict__ src, u16* __restrict__ dst, int n4) {
  int idx = blockIdx.x * blockDim.x + threadIdx.x;
  int stride = gridDim.x * blockDim.x;
  for (int i = idx; i < n4; i += stride) {
    float4 v = reinterpret_cast<const float4*>(src)[i];
    ushort4 o;
    o.x = f2bf(v.x); o.y = f2bf(v.y); o.z = f2bf(v.z); o.w = f2bf(v.w);
    reinterpret_cast<ushort4*>(dst)[i] = o;
  }
}

// ---------------- transpose f32 [K][N] -> bf16 [N][K] ----------------
__global__ void k_transpose_f32_bf16(const float* __restrict__ src, u16* __restrict__ dst,
                                     int K, int N) {
  __shared__ float tile[32][33];
  int n0 = blockIdx.x * 32, k0 = blockIdx.y * 32;
  int tx = threadIdx.x, ty = threadIdx.y;  // block (32,8)
  #pragma unroll
  for (int i = 0; i < 32; i += 8)
    tile[ty + i][tx] = src[(size_t)(k0 + ty + i) * N + n0 + tx];
  __syncthreads();
  #pragma unroll
  for (int i = 0; i < 32; i += 8)
    dst[(size_t)(n0 + ty + i) * K + k0 + tx] = f2bf(tile[tx][ty + i]);
}

// ---------------- bf16 GEMM, B^T input, 128x128 tile ----------------
// MODE 0: qkv projection -> scatter Q/K into [B][H][T][64], V into [B][H][64][T] (transposed), +bias
// MODE 1: out = A @ B + bias, f32 row-major
template<int MODE>
__global__ __launch_bounds__(256)
void k_gemm_bt(const u16* __restrict__ A, const u16* __restrict__ Bt,
               const float* __restrict__ bias,
               u16* __restrict__ q_out, u16* __restrict__ k_out, u16* __restrict__ v_out,
               float* __restrict__ c_out, int M, int N, int K)
{
  __shared__ __align__(16) u16 a_sh[128 * 64];
  __shared__ __align__(16) u16 b_sh[128 * 64];
  const int u = threadIdx.x;
  const int lane = u & 63;
  const int w = u >> 6;
  const int wr = w >> 1, wc = w & 1;
  const int m0 = blockIdx.y * 128;
  const int n0 = blockIdx.x * 128;
  const int r = lane & 15, q4 = lane >> 4;

  f32x4 acc[4][4];
  #pragma unroll
  for (int i = 0; i < 4; i++)
    #pragma unroll
    for (int j = 0; j < 4; j++) acc[i][j] = {0.f, 0.f, 0.f, 0.f};

  const int arow = u >> 3;        // 0..31
  const int acol = (u & 7) * 8;   // 0..56
  const u16* Ag = A + (size_t)(m0 + arow) * K + acol;
  const u16* Bg = Bt + (size_t)(n0 + arow) * K + acol;

  for (int k0 = 0; k0 < K; k0 += 64) {
    #pragma unroll
    for (int i = 0; i < 4; i++) {
      gload_lds16(Ag + (size_t)i * 32 * K + k0, &a_sh[(i * 32 + w * 8) * 64]);
      gload_lds16(Bg + (size_t)i * 32 * K + k0, &b_sh[(i * 32 + w * 8) * 64]);
    }
    __syncthreads();
    #pragma unroll
    for (int kc = 0; kc < 2; kc++) {
      bf16x8 af[4], bfr[4];
      #pragma unroll
      for (int m = 0; m < 4; m++)
        af[m] = *reinterpret_cast<const bf16x8*>(&a_sh[(wr * 64 + m * 16 + r) * 64 + kc * 32 + q4 * 8]);
      #pragma unroll
      for (int n = 0; n < 4; n++)
        bfr[n] = *reinterpret_cast<const bf16x8*>(&b_sh[(wc * 64 + n * 16 + r) * 64 + kc * 32 + q4 * 8]);
      #pragma unroll
      for (int m = 0; m < 4; m++)
        #pragma unroll
        for (int n = 0; n < 4; n++)
          acc[m][n] = __builtin_amdgcn_mfma_f32_16x16x32_bf16(af[m], bfr[n], acc[m][n], 0, 0, 0);
    }
    __syncthreads();
  }

  if (MODE == 0) {
    #pragma unroll
    for (int n = 0; n < 4; n++) {
      int gcol = n0 + wc * 64 + n * 16 + r;
      int which = gcol >> 10;   // uniform within fragment (16-aligned ranges)
      int rem = gcol & 1023;
      int h = rem >> 6, d = rem & 63;
      float bv = bias[gcol];
      #pragma unroll
      for (int m = 0; m < 4; m++) {
        #pragma unroll
        for (int reg = 0; reg < 4; reg++) {
          int grow = m0 + wr * 64 + m * 16 + q4 * 4 + reg;
          int b = grow >> 11, t = grow & 2047;
          u16 val = f2bf(acc[m][n][reg] + bv);
          if (which == 0)
            q_out[(((size_t)(b * NHEAD + h) * TT + t) << 6) + d] = val;
          else if (which == 1)
            k_out[(((size_t)(b * NHEAD + h) * TT + t) << 6) + d] = val;
          else  // V transposed: [b][h][d][t]
            v_out[(((size_t)(b * NHEAD + h) * HD + d) * TT) + t] = val;
        }
      }
    }
  } else {
    #pragma unroll
    for (int m = 0; m < 4; m++) {
      #pragma unroll
      for (int reg = 0; reg < 4; reg++) {
        int grow = m0 + wr * 64 + m * 16 + q4 * 4 + reg;
        #pragma unroll
        for (int n = 0; n < 4; n++) {
          int gcol = n0 + wc * 64 + n * 16 + r;
          c_out[(size_t)grow * N + gcol] = acc[m][n][reg] + bias[gcol];
        }
      }
    }
  }
}

// ---------------- causal flash attention ----------------
// 512 blocks of 256 (4 independent waves). Each wave owns 32 q-rows (two
// 16-col Q groups g=0,1). Swapped MFMA operands (S^T = mfma(K,Q)) keep the
// softmax fully in-lane. K tiles are register double-buffered (kfA/kfB) so
// global-load latency hides under the previous tile's compute. Barrier-free.
#define SCL2 0.18033688011112042f   // 0.125 * log2(e)

__device__ __forceinline__ void attn_tile(
    const u16* __restrict__ Kp, const u16* __restrict__ Vp,
    const bf16x8 (&kin)[8], bf16x8 (&kout)[8],
    const bf16x8 (&qf)[2][2], f32x4 (&of)[2][4],
    float (&m_run)[2], float (&lp)[2],
    u16* pw, int kt, bool diag, int q0, int r, int q4)
{
  // 1) prefetch next K tile into kout (overfetch past lastkt is harmless)
  {
    const u16* kp = Kp + (size_t)(kt + 1) * (64 * HD);
    #pragma unroll
    for (int n = 0; n < 4; n++) {
      kout[n * 2 + 0] = *reinterpret_cast<const bf16x8*>(kp + n * 1024);
      kout[n * 2 + 1] = *reinterpret_cast<const bf16x8*>(kp + n * 1024 + 32);
    }
  }

  // 2) S^T = mfma(K, Q): sf[g][n][reg] = S[k][q], lane's q = q0+g*16+r
  f32x4 sf[2][4];
  __builtin_amdgcn_s_setprio(1);
  #pragma unroll
  for (int g = 0; g < 2; g++)
    #pragma unroll
    for (int n = 0; n < 4; n++) {
      f32x4 a = {0.f, 0.f, 0.f, 0.f};
      a = __builtin_amdgcn_mfma_f32_16x16x32_bf16(kin[n * 2 + 0], qf[g][0], a, 0, 0, 0);
      a = __builtin_amdgcn_mfma_f32_16x16x32_bf16(kin[n * 2 + 1], qf[g][1], a, 0, 0, 0);
      sf[g][n] = a;
    }
  __builtin_amdgcn_s_setprio(0);

  // 3) V fragments for this tile (latency hides under softmax)
  bf16x8 vf[2][4];
  #pragma unroll
  for (int d0 = 0; d0 < 4; d0++) {
    const u16* vp = Vp + (size_t)d0 * (16 * TT) + kt * 64;
    vf[0][d0] = *reinterpret_cast<const bf16x8*>(vp);
    vf[1][d0] = *reinterpret_cast<const bf16x8*>(vp + 32);
  }

  // 4) per-group in-lane online softmax
  #pragma unroll
  for (int g = 0; g < 2; g++) {
    const int myq = q0 + g * 16 + r;
    #pragma unroll
    for (int n = 0; n < 4; n++)
      #pragma unroll
      for (int reg = 0; reg < 4; reg++) {
        float s = sf[g][n][reg] * SCL2;
        if (diag) {
          int kg = kt * 64 + n * 16 + q4 * 4 + reg;
          if (kg > myq) s = -1e30f;
        }
        sf[g][n][reg] = s;
      }
    float a0 = fmaxf(fmaxf(sf[g][0][0], sf[g][0][1]), fmaxf(sf[g][0][2], sf[g][0][3]));
    float a1 = fmaxf(fmaxf(sf[g][1][0], sf[g][1][1]), fmaxf(sf[g][1][2], sf[g][1][3]));
    float a2 = fmaxf(fmaxf(sf[g][2][0], sf[g][2][1]), fmaxf(sf[g][2][2], sf[g][2][3]));
    float a3 = fmaxf(fmaxf(sf[g][3][0], sf[g][3][1]), fmaxf(sf[g][3][2], sf[g][3][3]));
    float mt = fmaxf(fmaxf(a0, a1), fmaxf(a2, a3));
    mt = fmaxf(mt, __shfl_xor(mt, 16));
    mt = fmaxf(mt, __shfl_xor(mt, 32));
    float mnew = fmaxf(m_run[g], mt);
    float alpha = __builtin_amdgcn_exp2f(m_run[g] - mnew);
    m_run[g] = mnew;

    f32x4 ss = {0.f, 0.f, 0.f, 0.f};
    #pragma unroll
    for (int n = 0; n < 4; n++) {
      #pragma unroll
      for (int reg = 0; reg < 4; reg++)
        sf[g][n][reg] = __builtin_amdgcn_exp2f(sf[g][n][reg] - mnew);
      ss += sf[g][n];
    }
    lp[g] = lp[g] * alpha + ((ss[0] + ss[1]) + (ss[2] + ss[3]));

    #pragma unroll
    for (int d0 = 0; d0 < 4; d0++)
      #pragma unroll
      for (int reg = 0; reg < 4; reg++)
        of[g][d0][reg] *= alpha;

    // P -> per-wave LDS [q][k] (packed 8B writes; no barrier needed)
    #pragma unroll
    for (int n = 0; n < 4; n++) {
      uint2 pk;
      pk.x = pack2bf(sf[g][n][0], sf[g][n][1]);
      pk.y = pack2bf(sf[g][n][2], sf[g][n][3]);
      *reinterpret_cast<uint2*>(&pw[(g * 16 + r) * 72 + n * 16 + q4 * 4]) = pk;
    }
  }

  // 5) O^T += mfma(V, P)
  #pragma unroll
  for (int g = 0; g < 2; g++)
    #pragma unroll
    for (int kc = 0; kc < 2; kc++) {
      bf16x8 pa = *reinterpret_cast<const bf16x8*>(&pw[(g * 16 + r) * 72 + kc * 32 + q4 * 8]);
      #pragma unroll
      for (int d0 = 0; d0 < 4; d0++)
        of[g][d0] = __builtin_amdgcn_mfma_f32_16x16x32_bf16(vf[kc][d0], pa, of[g][d0], 0, 0, 0);
    }
}

__global__ __launch_bounds__(256)
void k_attn(const u16* __restrict__ Q, const u16* __restrict__ Kk,
            const u16* __restrict__ Vt, u16* __restrict__ Y)
{
  __shared__ __align__(16) u16 p_sh[4][32 * 72];   // per-wave [32 q][64 k] P tile

  const int u = threadIdx.x;
  const int lane = u & 63;
  const int w = u >> 6;
  const int r = lane & 15, q4 = lane >> 4;
  const int task = (blockIdx.x & 7) * 64 + (blockIdx.x >> 3);   // XCD swizzle (512 blocks)
  const int bh = task >> 4;
  const int i = task & 15;
  const int wt = (w < 2) ? (2 * i + w) : (63 - 2 * i - (w & 1));  // balanced causal map, 0..63
  const int b = bh >> 4, h = bh & 15;
  const size_t head_off = (size_t)bh * TT * HD;   // Q,K: [t][d];  Vt: [d][t]
  const int q0 = wt * 32;
  const int lastkt = wt >> 1;

  const u16* Kp = Kk + head_off + (size_t)r * HD + q4 * 8;
  const u16* Vp = Vt + head_off + (size_t)r * TT + q4 * 8;

  bf16x8 qf[2][2];
  #pragma unroll
  for (int g = 0; g < 2; g++) {
    const u16* qp = &Q[head_off + (size_t)(q0 + g * 16 + r) * HD + q4 * 8];
    qf[g][0] = *reinterpret_cast<const bf16x8*>(qp);
    qf[g][1] = *reinterpret_cast<const bf16x8*>(qp + 32);
  }

  f32x4 of[2][4];
  #pragma unroll
  for (int g = 0; g < 2; g++)
    #pragma unroll
    for (int k = 0; k < 4; k++) of[g][k] = {0.f, 0.f, 0.f, 0.f};
  float m_run[2] = {-1e30f, -1e30f};
  float lp[2] = {0.f, 0.f};

  u16* pw = &p_sh[w][0];

  // prologue: load K tile 0 into kfA
  bf16x8 kfA[8], kfB[8];
  #pragma unroll
  for (int n = 0; n < 4; n++) {
    kfA[n * 2 + 0] = *reinterpret_cast<const bf16x8*>(Kp + n * 1024);
    kfA[n * 2 + 1] = *reinterpret_cast<const bf16x8*>(Kp + n * 1024 + 32);
  }

  for (int kt = 0; kt <= lastkt; kt += 2) {
    attn_tile(Kp, Vp, kfA, kfB, qf, of, m_run, lp, pw, kt, kt == lastkt, q0, r, q4);
    if (kt + 1 <= lastkt)
      attn_tile(Kp, Vp, kfB, kfA, qf, of, m_run, lp, pw, kt + 1, kt + 1 == lastkt, q0, r, q4);
  }

  // epilogue: reduce per-lane partial l across q4 lanes, packed stores
  #pragma unroll
  for (int g = 0; g < 2; g++) {
    float l = lp[g];
    l += __shfl_xor(l, 16);
    l += __shfl_xor(l, 32);
    float inv = 1.0f / l;
    const int t = q0 + g * 16 + r;
    #pragma unroll
    for (int d0 = 0; d0 < 4; d0++) {
      uint2 pk;
      pk.x = pack2bf(of[g][d0][0] * inv, of[g][d0][1] * inv);
      pk.y = pack2bf(of[g][d0][2] * inv, of[g][d0][3] * inv);
      *reinterpret_cast<uint2*>(&Y[((size_t)(b * TT + t) << 10) + h * 64 + d0 * 16 + q4 * 4]) = pk;
    }
  }
}

// ---------------- host launcher ----------------
extern "C" void kernel_launch(void* const* d_in, const int* in_sizes, int n_in,
                              void* d_out, int out_size, void* d_ws, size_t ws_size,
                              hipStream_t stream) {
  const float* x     = (const float*)d_in[0];
  const float* w_qkv = (const float*)d_in[1];
  const float* b_qkv = (const float*)d_in[2];
  const float* w_out = (const float*)d_in[3];
  const float* b_out = (const float*)d_in[4];
  float* out = (float*)d_out;

  uint8_t* ws = (uint8_t*)d_ws;
  u16* xb    = (u16*)(ws);                    // 8 MB  (reused as y_heads later)
  u16* wqkvT = (u16*)(ws + (8u  << 20));      // 6 MB
  u16* woutT = (u16*)(ws + (14u << 20));      // 2 MB
  u16* Qh    = (u16*)(ws + (16u << 20));      // 8 MB
  u16* Kh    = (u16*)(ws + (24u << 20));      // 8 MB
  u16* Vth   = (u16*)(ws + (32u << 20));      // 8 MB  (transposed V; also absorbs K prefetch overfetch)

  k_f32_to_bf16<<<1024, 256, 0, stream>>>(x, xb, (MR * D_MODEL) / 4);
  k_transpose_f32_bf16<<<dim3(3 * D_MODEL / 32, D_MODEL / 32), dim3(32, 8), 0, stream>>>(
      w_qkv, wqkvT, D_MODEL, 3 * D_MODEL);
  k_transpose_f32_bf16<<<dim3(D_MODEL / 32, D_MODEL / 32), dim3(32, 8), 0, stream>>>(
      w_out, woutT, D_MODEL, D_MODEL);

  k_gemm_bt<0><<<dim3(3 * D_MODEL / 128, MR / 128), 256, 0, stream>>>(
      xb, wqkvT, b_qkv, Qh, Kh, Vth, nullptr, MR, 3 * D_MODEL, D_MODEL);

  u16* Yh = xb;  // reuse x-bf16 region
  k_attn<<<dim3(BB * NHEAD * 16), 256, 0, stream>>>(Qh, Kh, Vth, Yh);

  k_gemm_bt<1><<<dim3(D_MODEL / 128, MR / 128), 256, 0, stream>>>(
      Yh, woutT, b_out, nullptr, nullptr, nullptr, out, MR, D_MODEL, D_MODEL);
}

// Round 6
// 172.209 us; speedup vs baseline: 1.5012x; 1.0761x over previous
//
#include <hip/hip_runtime.h>
#include <stdint.h>

#define D_MODEL 1024
#define NHEAD 16
#define HD 64
#define BB 2
#define TT 2048
#define MR (BB*TT)   // 4096 rows

typedef unsigned short u16;
typedef __bf16 bf16x8 __attribute__((ext_vector_type(8)));
typedef u16 u16x8 __attribute__((ext_vector_type(8)));
typedef float f32x4 __attribute__((ext_vector_type(4)));

__device__ __forceinline__ u16 f2bf(float f) {
  union { float f; unsigned u; } v; v.f = f;
  unsigned r = v.u + 0x7FFFu + ((v.u >> 16) & 1u);
  return (u16)(r >> 16);
}
__device__ __forceinline__ unsigned pack2bf(float a, float b) {
  return (unsigned)f2bf(a) | ((unsigned)f2bf(b) << 16);
}

__device__ __forceinline__ void gload_lds16(const void* g, void* l) {
  __builtin_amdgcn_global_load_lds(
      (const __attribute__((address_space(1))) void*)g,
      (__attribute__((address_space(3))) void*)l, 16, 0, 0);
}

// ---------------- f32 -> bf16 convert (vectorized) ----------------
__global__ void k_f32_to_bf16(const float* __restrict__ src, u16* __restrict__ dst, int n4) {
  int idx = blockIdx.x * blockDim.x + threadIdx.x;
  int stride = gridDim.x * blockDim.x;
  for (int i = idx; i < n4; i += stride) {
    float4 v = reinterpret_cast<const float4*>(src)[i];
    ushort4 o;
    o.x = f2bf(v.x); o.y = f2bf(v.y); o.z = f2bf(v.z); o.w = f2bf(v.w);
    reinterpret_cast<ushort4*>(dst)[i] = o;
  }
}

// ---------------- transpose f32 [K][N] -> bf16 [N][K] ----------------
__global__ void k_transpose_f32_bf16(const float* __restrict__ src, u16* __restrict__ dst,
                                     int K, int N) {
  __shared__ float tile[32][33];
  int n0 = blockIdx.x * 32, k0 = blockIdx.y * 32;
  int tx = threadIdx.x, ty = threadIdx.y;  // block (32,8)
  #pragma unroll
  for (int i = 0; i < 32; i += 8)
    tile[ty + i][tx] = src[(size_t)(k0 + ty + i) * N + n0 + tx];
  __syncthreads();
  #pragma unroll
  for (int i = 0; i < 32; i += 8)
    dst[(size_t)(n0 + ty + i) * K + k0 + tx] = f2bf(tile[tx][ty + i]);
}

// ---------------- bf16 GEMM, B^T input, 128x128 tile ----------------
// MODE 0: qkv projection -> scatter Q/K into [B][H][T][64], V into [B][H][64][T] (transposed), +bias
// MODE 1: out = A @ B + bias, f32 row-major
template<int MODE>
__global__ __launch_bounds__(256)
void k_gemm_bt(const u16* __restrict__ A, const u16* __restrict__ Bt,
               const float* __restrict__ bias,
               u16* __restrict__ q_out, u16* __restrict__ k_out, u16* __restrict__ v_out,
               float* __restrict__ c_out, int M, int N, int K)
{
  __shared__ __align__(16) u16 a_sh[128 * 64];
  __shared__ __align__(16) u16 b_sh[128 * 64];
  const int u = threadIdx.x;
  const int lane = u & 63;
  const int w = u >> 6;
  const int wr = w >> 1, wc = w & 1;
  const int m0 = blockIdx.y * 128;
  const int n0 = blockIdx.x * 128;
  const int r = lane & 15, q4 = lane >> 4;

  f32x4 acc[4][4];
  #pragma unroll
  for (int i = 0; i < 4; i++)
    #pragma unroll
    for (int j = 0; j < 4; j++) acc[i][j] = {0.f, 0.f, 0.f, 0.f};

  const int arow = u >> 3;        // 0..31
  const int acol = (u & 7) * 8;   // 0..56
  const u16* Ag = A + (size_t)(m0 + arow) * K + acol;
  const u16* Bg = Bt + (size_t)(n0 + arow) * K + acol;

  for (int k0 = 0; k0 < K; k0 += 64) {
    #pragma unroll
    for (int i = 0; i < 4; i++) {
      gload_lds16(Ag + (size_t)i * 32 * K + k0, &a_sh[(i * 32 + w * 8) * 64]);
      gload_lds16(Bg + (size_t)i * 32 * K + k0, &b_sh[(i * 32 + w * 8) * 64]);
    }
    __syncthreads();
    #pragma unroll
    for (int kc = 0; kc < 2; kc++) {
      bf16x8 af[4], bfr[4];
      #pragma unroll
      for (int m = 0; m < 4; m++)
        af[m] = *reinterpret_cast<const bf16x8*>(&a_sh[(wr * 64 + m * 16 + r) * 64 + kc * 32 + q4 * 8]);
      #pragma unroll
      for (int n = 0; n < 4; n++)
        bfr[n] = *reinterpret_cast<const bf16x8*>(&b_sh[(wc * 64 + n * 16 + r) * 64 + kc * 32 + q4 * 8]);
      #pragma unroll
      for (int m = 0; m < 4; m++)
        #pragma unroll
        for (int n = 0; n < 4; n++)
          acc[m][n] = __builtin_amdgcn_mfma_f32_16x16x32_bf16(af[m], bfr[n], acc[m][n], 0, 0, 0);
    }
    __syncthreads();
  }

  if (MODE == 0) {
    #pragma unroll
    for (int n = 0; n < 4; n++) {
      int gcol = n0 + wc * 64 + n * 16 + r;
      int which = gcol >> 10;   // uniform within fragment (16-aligned ranges)
      int rem = gcol & 1023;
      int h = rem >> 6, d = rem & 63;
      float bv = bias[gcol];
      #pragma unroll
      for (int m = 0; m < 4; m++) {
        #pragma unroll
        for (int reg = 0; reg < 4; reg++) {
          int grow = m0 + wr * 64 + m * 16 + q4 * 4 + reg;
          int b = grow >> 11, t = grow & 2047;
          u16 val = f2bf(acc[m][n][reg] + bv);
          if (which == 0)
            q_out[(((size_t)(b * NHEAD + h) * TT + t) << 6) + d] = val;
          else if (which == 1)
            k_out[(((size_t)(b * NHEAD + h) * TT + t) << 6) + d] = val;
          else  // V transposed: [b][h][d][t]
            v_out[(((size_t)(b * NHEAD + h) * HD + d) * TT) + t] = val;
        }
      }
    }
  } else {
    #pragma unroll
    for (int m = 0; m < 4; m++) {
      #pragma unroll
      for (int reg = 0; reg < 4; reg++) {
        int grow = m0 + wr * 64 + m * 16 + q4 * 4 + reg;
        #pragma unroll
        for (int n = 0; n < 4; n++) {
          int gcol = n0 + wc * 64 + n * 16 + r;
          c_out[(size_t)grow * N + gcol] = acc[m][n][reg] + bias[gcol];
        }
      }
    }
  }
}

// ---------------- causal flash attention ----------------
// 256 blocks of 512 (8 independent waves). Each wave owns 32 q-rows. SIMD s
// hosts waves s (tile 4i+s, cheap) and s+4 (tile 63-4i-s, expensive): per-SIMD
// work sums to a constant -> no intra-block or inter-block imbalance.
// Swapped MFMA operands (S^T = mfma(K,Q)) keep softmax in-lane; K tiles are
// register double-buffered; barrier-free.
#define SCL2 0.18033688011112042f   // 0.125 * log2(e)

__device__ __forceinline__ void attn_tile(
    const u16* __restrict__ Kp, const u16* __restrict__ Vp,
    const bf16x8 (&kin)[8], bf16x8 (&kout)[8],
    const bf16x8 (&qf)[2][2], f32x4 (&of)[2][4],
    float (&m_run)[2], float (&lp)[2],
    u16* pw, int kt, bool diag, int q0, int r, int q4)
{
  // 1) prefetch next K tile into kout (overfetch past lastkt is harmless)
  {
    const u16* kp = Kp + (size_t)(kt + 1) * (64 * HD);
    #pragma unroll
    for (int n = 0; n < 4; n++) {
      kout[n * 2 + 0] = *reinterpret_cast<const bf16x8*>(kp + n * 1024);
      kout[n * 2 + 1] = *reinterpret_cast<const bf16x8*>(kp + n * 1024 + 32);
    }
  }

  // 2) S^T = mfma(K, Q): sf[g][n][reg] = S[k][q], lane's q = q0+g*16+r
  f32x4 sf[2][4];
  __builtin_amdgcn_s_setprio(1);
  #pragma unroll
  for (int g = 0; g < 2; g++)
    #pragma unroll
    for (int n = 0; n < 4; n++) {
      f32x4 a = {0.f, 0.f, 0.f, 0.f};
      a = __builtin_amdgcn_mfma_f32_16x16x32_bf16(kin[n * 2 + 0], qf[g][0], a, 0, 0, 0);
      a = __builtin_amdgcn_mfma_f32_16x16x32_bf16(kin[n * 2 + 1], qf[g][1], a, 0, 0, 0);
      sf[g][n] = a;
    }
  __builtin_amdgcn_s_setprio(0);

  // 3) V fragments for this tile (latency hides under softmax)
  bf16x8 vf[2][4];
  #pragma unroll
  for (int d0 = 0; d0 < 4; d0++) {
    const u16* vp = Vp + (size_t)d0 * (16 * TT) + kt * 64;
    vf[0][d0] = *reinterpret_cast<const bf16x8*>(vp);
    vf[1][d0] = *reinterpret_cast<const bf16x8*>(vp + 32);
  }

  // 4) per-group in-lane online softmax
  #pragma unroll
  for (int g = 0; g < 2; g++) {
    const int myq = q0 + g * 16 + r;
    #pragma unroll
    for (int n = 0; n < 4; n++)
      #pragma unroll
      for (int reg = 0; reg < 4; reg++) {
        float s = sf[g][n][reg] * SCL2;
        if (diag) {
          int kg = kt * 64 + n * 16 + q4 * 4 + reg;
          if (kg > myq) s = -1e30f;
        }
        sf[g][n][reg] = s;
      }
    float a0 = fmaxf(fmaxf(sf[g][0][0], sf[g][0][1]), fmaxf(sf[g][0][2], sf[g][0][3]));
    float a1 = fmaxf(fmaxf(sf[g][1][0], sf[g][1][1]), fmaxf(sf[g][1][2], sf[g][1][3]));
    float a2 = fmaxf(fmaxf(sf[g][2][0], sf[g][2][1]), fmaxf(sf[g][2][2], sf[g][2][3]));
    float a3 = fmaxf(fmaxf(sf[g][3][0], sf[g][3][1]), fmaxf(sf[g][3][2], sf[g][3][3]));
    float mt = fmaxf(fmaxf(a0, a1), fmaxf(a2, a3));
    mt = fmaxf(mt, __shfl_xor(mt, 16));
    mt = fmaxf(mt, __shfl_xor(mt, 32));
    float mnew = fmaxf(m_run[g], mt);
    float alpha = __builtin_amdgcn_exp2f(m_run[g] - mnew);
    m_run[g] = mnew;

    f32x4 ss = {0.f, 0.f, 0.f, 0.f};
    #pragma unroll
    for (int n = 0; n < 4; n++) {
      #pragma unroll
      for (int reg = 0; reg < 4; reg++)
        sf[g][n][reg] = __builtin_amdgcn_exp2f(sf[g][n][reg] - mnew);
      ss += sf[g][n];
    }
    lp[g] = lp[g] * alpha + ((ss[0] + ss[1]) + (ss[2] + ss[3]));

    #pragma unroll
    for (int d0 = 0; d0 < 4; d0++)
      #pragma unroll
      for (int reg = 0; reg < 4; reg++)
        of[g][d0][reg] *= alpha;

    // P -> per-wave LDS [q][k] (packed 8B writes; no barrier needed)
    #pragma unroll
    for (int n = 0; n < 4; n++) {
      uint2 pk;
      pk.x = pack2bf(sf[g][n][0], sf[g][n][1]);
      pk.y = pack2bf(sf[g][n][2], sf[g][n][3]);
      *reinterpret_cast<uint2*>(&pw[(g * 16 + r) * 72 + n * 16 + q4 * 4]) = pk;
    }
  }

  // 5) O^T += mfma(V, P)
  #pragma unroll
  for (int g = 0; g < 2; g++)
    #pragma unroll
    for (int kc = 0; kc < 2; kc++) {
      bf16x8 pa = *reinterpret_cast<const bf16x8*>(&pw[(g * 16 + r) * 72 + kc * 32 + q4 * 8]);
      #pragma unroll
      for (int d0 = 0; d0 < 4; d0++)
        of[g][d0] = __builtin_amdgcn_mfma_f32_16x16x32_bf16(vf[kc][d0], pa, of[g][d0], 0, 0, 0);
    }
}

__global__ __launch_bounds__(512)
void k_attn(const u16* __restrict__ Q, const u16* __restrict__ Kk,
            const u16* __restrict__ Vt, u16* __restrict__ Y)
{
  __shared__ __align__(16) u16 p_sh[8][32 * 72];   // per-wave [32 q][64 k] P tile

  const int u = threadIdx.x;
  const int lane = u & 63;
  const int w = u >> 6;                 // 0..7
  const int r = lane & 15, q4 = lane >> 4;
  // XCD-resident head map: all 8 blocks of a head share blockIdx&7
  const int xcd = blockIdx.x & 7;
  const int j = blockIdx.x >> 3;        // 0..31
  const int bh = xcd * 4 + (j >> 3);    // 0..31
  const int i = j & 7;                  // block index within head, 0..7
  const int s = w & 3, half = w >> 2;
  const int wt = half ? (63 - (4 * i + s)) : (4 * i + s);   // SIMD s: cheap+expensive pair
  const int b = bh >> 4, h = bh & 15;
  const size_t head_off = (size_t)bh * TT * HD;   // Q,K: [t][d];  Vt: [d][t]
  const int q0 = wt * 32;
  const int lastkt = wt >> 1;

  const u16* Kp = Kk + head_off + (size_t)r * HD + q4 * 8;
  const u16* Vp = Vt + head_off + (size_t)r * TT + q4 * 8;

  bf16x8 qf[2][2];
  #pragma unroll
  for (int g = 0; g < 2; g++) {
    const u16* qp = &Q[head_off + (size_t)(q0 + g * 16 + r) * HD + q4 * 8];
    qf[g][0] = *reinterpret_cast<const bf16x8*>(qp);
    qf[g][1] = *reinterpret_cast<const bf16x8*>(qp + 32);
  }

  f32x4 of[2][4];
  #pragma unroll
  for (int g = 0; g < 2; g++)
    #pragma unroll
    for (int k = 0; k < 4; k++) of[g][k] = {0.f, 0.f, 0.f, 0.f};
  float m_run[2] = {-1e30f, -1e30f};
  float lp[2] = {0.f, 0.f};

  u16* pw = &p_sh[w][0];

  // prologue: load K tile 0 into kfA
  bf16x8 kfA[8], kfB[8];
  #pragma unroll
  for (int n = 0; n < 4; n++) {
    kfA[n * 2 + 0] = *reinterpret_cast<const bf16x8*>(Kp + n * 1024);
    kfA[n * 2 + 1] = *reinterpret_cast<const bf16x8*>(Kp + n * 1024 + 32);
  }

  for (int kt = 0; kt <= lastkt; kt += 2) {
    attn_tile(Kp, Vp, kfA, kfB, qf, of, m_run, lp, pw, kt, kt == lastkt, q0, r, q4);
    if (kt + 1 <= lastkt)
      attn_tile(Kp, Vp, kfB, kfA, qf, of, m_run, lp, pw, kt + 1, kt + 1 == lastkt, q0, r, q4);
  }

  // epilogue: reduce per-lane partial l across q4 lanes, packed stores
  #pragma unroll
  for (int g = 0; g < 2; g++) {
    float l = lp[g];
    l += __shfl_xor(l, 16);
    l += __shfl_xor(l, 32);
    float inv = 1.0f / l;
    const int t = q0 + g * 16 + r;
    #pragma unroll
    for (int d0 = 0; d0 < 4; d0++) {
      uint2 pk;
      pk.x = pack2bf(of[g][d0][0] * inv, of[g][d0][1] * inv);
      pk.y = pack2bf(of[g][d0][2] * inv, of[g][d0][3] * inv);
      *reinterpret_cast<uint2*>(&Y[((size_t)(b * TT + t) << 10) + h * 64 + d0 * 16 + q4 * 4]) = pk;
    }
  }
}

// ---------------- host launcher ----------------
extern "C" void kernel_launch(void* const* d_in, const int* in_sizes, int n_in,
                              void* d_out, int out_size, void* d_ws, size_t ws_size,
                              hipStream_t stream) {
  const float* x     = (const float*)d_in[0];
  const float* w_qkv = (const float*)d_in[1];
  const float* b_qkv = (const float*)d_in[2];
  const float* w_out = (const float*)d_in[3];
  const float* b_out = (const float*)d_in[4];
  float* out = (float*)d_out;

  uint8_t* ws = (uint8_t*)d_ws;
  u16* xb    = (u16*)(ws);                    // 8 MB  (reused as y_heads later)
  u16* wqkvT = (u16*)(ws + (8u  << 20));      // 6 MB
  u16* woutT = (u16*)(ws + (14u << 20));      // 2 MB
  u16* Qh    = (u16*)(ws + (16u << 20));      // 8 MB
  u16* Kh    = (u16*)(ws + (24u << 20));      // 8 MB
  u16* Vth   = (u16*)(ws + (32u << 20));      // 8 MB  (transposed V; also absorbs K prefetch overfetch)

  k_f32_to_bf16<<<1024, 256, 0, stream>>>(x, xb, (MR * D_MODEL) / 4);
  k_transpose_f32_bf16<<<dim3(3 * D_MODEL / 32, D_MODEL / 32), dim3(32, 8), 0, stream>>>(
      w_qkv, wqkvT, D_MODEL, 3 * D_MODEL);
  k_transpose_f32_bf16<<<dim3(D_MODEL / 32, D_MODEL / 32), dim3(32, 8), 0, stream>>>(
      w_out, woutT, D_MODEL, D_MODEL);

  k_gemm_bt<0><<<dim3(3 * D_MODEL / 128, MR / 128), 256, 0, stream>>>(
      xb, wqkvT, b_qkv, Qh, Kh, Vth, nullptr, MR, 3 * D_MODEL, D_MODEL);

  u16* Yh = xb;  // reuse x-bf16 region
  k_attn<<<dim3(256), dim3(512), 0, stream>>>(Qh, Kh, Vth, Yh);

  k_gemm_bt<1><<<dim3(D_MODEL / 128, MR / 128), 256, 0, stream>>>(
      Yh, woutT, b_out, nullptr, nullptr, nullptr, out, MR, D_MODEL, D_MODEL);
}